// Round 11
// baseline (16.024 us; speedup 1.0000x reference)
//
#include <hip/hip_runtime.h>
#include <math.h>

#define B_  4
#define CI  8
#define HH  128
#define WW  128
#define CO  16
#define KH  5
#define KW  5
#define HO  124
#define WO  124

#define TILE_X 16     // px cols per block (8 tx-groups of 2 px)
#define TILE_Y 8      // px rows per block
#define ROWF   20     // LDS row: 16 + 4 halo floats = 5 float4
#define THREADS 512   // 8 waves; wave w owns output channels {2w, 2w+1}

__global__ __launch_bounds__(THREADS, 4)
void maxplus_conv11(const float* __restrict__ img,
                    const float* __restrict__ kern,
                    float* __restrict__ out)
{
    // img tile rows y0..y0+11, cols x0..x0+19, -INF outside img. 8*12*20*4 = 7.7 KB
    __shared__ __align__(16) float ilds[CI][TILE_Y + KH - 1][ROWF];

    const int tid = threadIdx.x;
    const int x0  = blockIdx.x * TILE_X;
    const int y0  = blockIdx.y * TILE_Y;
    const int b   = blockIdx.z;

    // ---- stage img tile: 8c * 12r * 5 f4 = 480 float4, ONE round ----
    const float* imgb = img + (size_t)b * CI * HH * WW;
    if (tid < CI * 12 * 5) {
        const int c   = tid / 60;
        const int rem = tid - c * 60;
        const int r   = rem / 5;
        const int f4  = rem - r * 5;
        const int gy = y0 + r;
        const int gx = x0 + f4 * 4;         // 16B-aligned (x0 % 16 == 0)
        float4 v;
        if (gy < HH && gx < WW) {           // gx<128 => gx<=124 => gx+3<=127
            v = *(const float4*)&imgb[(c * HH + gy) * WW + gx];
        } else {
            v.x = v.y = v.z = v.w = -INFINITY;
        }
        *(float4*)&ilds[c][r][f4 * 4] = v;
    }
    __syncthreads();

    const int lane = tid & 63;
    const int tx   = lane & 7;          // 2 px each: x = x0 + tx*2 + {0,1}
    const int ty   = lane >> 3;         // output row y0 + ty  (0..7)
    // wave-uniform o-pair: wave w -> o = 2w, 2w+1
    const int o0 = __builtin_amdgcn_readfirstlane((tid >> 6) << 1);

    const float* w0p = kern + (size_t)o0 * (CI * KH * KW);
    const float* w1p = w0p + CI * KH * KW;

    float acc00 = -INFINITY, acc01 = -INFINITY;  // px0: o0, o1
    float acc10 = -INFINITY, acc11 = -INFINITY;  // px1: o0, o1

    #pragma unroll 1
    for (int c = 0; c < CI; ++c) {
        // this channel's 50 weights (uniform addresses)
        float w0[25], w1[25];
        #pragma unroll
        for (int t = 0; t < 25; ++t) {
            w0[t] = w0p[c * 25 + t];
            w1[t] = w1p[c * 25 + t];
        }
        // this channel's img window: 3 x ds_read_b64 per row (8B-aligned)
        float2 vA[5], vB[5], vC[5];
        #pragma unroll
        for (int i = 0; i < KH; ++i) {
            const float* vp = &ilds[c][ty + i][tx * 2];
            vA[i] = *(const float2*)vp;
            vB[i] = *(const float2*)(vp + 2);
            vC[i] = *(const float2*)(vp + 4);
        }
        #pragma unroll
        for (int i = 0; i < KH; ++i) {
            const float v[6] = {vA[i].x, vA[i].y, vB[i].x, vB[i].y, vC[i].x, vC[i].y};
            #pragma unroll
            for (int p = 0; p < 2; ++p) {
                float T0[5], T1[5];
                #pragma unroll
                for (int j = 0; j < KW; ++j) {
                    const int wi = (4 - i) * KW + (4 - j);   // flipped tap
                    T0[j] = v[p + j] + w0[wi];
                    T1[j] = v[p + j] + w1[wi];
                }
                float* a0 = p ? &acc10 : &acc00;
                float* a1 = p ? &acc11 : &acc01;
                *a0 = fmaxf(fmaxf(fmaxf(*a0, T0[0]), T0[1]),
                            fmaxf(fmaxf(T0[2], T0[3]), T0[4]));
                *a1 = fmaxf(fmaxf(fmaxf(*a1, T1[0]), T1[1]),
                            fmaxf(fmaxf(T1[2], T1[3]), T1[4]));
            }
        }
    }

    // ---- write out: float2 per o (x even, 8B-aligned) ----
    const int y = y0 + ty;
    const int x = x0 + tx * 2;
    if (y < HO && x < WO) {              // x even => x+1 <= 123 whenever x < 124
        float2 s0; s0.x = acc00; s0.y = acc10;
        float2 s1; s1.x = acc01; s1.y = acc11;
        *(float2*)&out[(((size_t)b * CO + o0) * HO + y) * WO + x] = s0;
        *(float2*)&out[(((size_t)b * CO + o0 + 1) * HO + y) * WO + x] = s1;
    }
}

extern "C" void kernel_launch(void* const* d_in, const int* in_sizes, int n_in,
                              void* d_out, int out_size, void* d_ws, size_t ws_size,
                              hipStream_t stream)
{
    const float* img  = (const float*)d_in[0];
    const float* kern = (const float*)d_in[1];
    float* out = (float*)d_out;

    dim3 grid((WO + TILE_X - 1) / TILE_X,   // 8
              (HO + TILE_Y - 1) / TILE_Y,   // 16
              B_);                          // 4  -> 512 blocks
    dim3 block(THREADS);
    maxplus_conv11<<<grid, block, 0, stream>>>(img, kern, out);
}